// Round 15
// baseline (203.479 us; speedup 1.0000x reference)
//
#include <hip/hip_runtime.h>
#include <hip/hip_cooperative_groups.h>

namespace cg = cooperative_groups;

#define BATCH 8
#define ROWS  2048
#define WIDTH 4096
#define COLS  4096
#define KB    1024   // WIDTH/4 gating blocks along k
#define CBV   1024   // COLS/4  float4s per W row
#define ZPART 32
#define RCH   64     // rows per colsum strip
#define NDOT  256

typedef float f32x4 __attribute__((ext_vector_type(4)));

// ---- colsum strip s: register-held column sums -----------------------------
__device__ __forceinline__ f32x4 do_colsum(const f32x4* __restrict__ X, int s, int t) {
    const int k4 = (s & 3) * 256 + t;
    const int b  = (s >> 2) & 7;
    const int z  = s >> 5;
    const f32x4* p = X + (size_t)(b * ROWS + z * RCH) * (WIDTH / 4) + k4;
    f32x4 a = {0.f, 0.f, 0.f, 0.f};
#pragma unroll 8
    for (int r = 0; r < RCH; ++r) {
        f32x4 v = p[(size_t)r * (WIDTH / 4)];
        a.x += v.x; a.y += v.y; a.z += v.z; a.w += v.w;
    }
    return a;
}

// ---- gate row kb: wg[b, 4kb+j] = sum_c W[4kb+j,c] * G[b,kb,c/4] ------------
__device__ __forceinline__ void do_gate(const f32x4* __restrict__ Wv,
                                        const f32x4* __restrict__ Gv,
                                        float* __restrict__ wg,
                                        float lds[4][32], int kb, int t) {
    const int lane = t & 63, wv = t >> 6;

    f32x4 g[8];
#pragma unroll
    for (int b = 0; b < 8; ++b)
        g[b] = Gv[((size_t)(b * KB + kb) << 8) + t];

    float w4[4][4];  // 4-col block sums of W, loaded two rows at a time
#pragma unroll
    for (int jp = 0; jp < 2; ++jp) {
        f32x4 wj[2][4];
#pragma unroll
        for (int j = 0; j < 2; ++j)
#pragma unroll
            for (int m = 0; m < 4; ++m)
                wj[j][m] = Wv[(size_t)(4 * kb + 2 * jp + j) * CBV + 4 * t + m];
#pragma unroll
        for (int j = 0; j < 2; ++j)
#pragma unroll
            for (int m = 0; m < 4; ++m)
                w4[2 * jp + j][m] = (wj[j][m].x + wj[j][m].y) + (wj[j][m].z + wj[j][m].w);
    }

    float acc[8][4];
#pragma unroll
    for (int b = 0; b < 8; ++b)
#pragma unroll
        for (int j = 0; j < 4; ++j)
            acc[b][j] = g[b].x * w4[j][0] + g[b].y * w4[j][1] +
                        g[b].z * w4[j][2] + g[b].w * w4[j][3];

#pragma unroll
    for (int v = 0; v < 32; ++v) {
        float x = acc[v >> 2][v & 3];
#pragma unroll
        for (int o = 1; o < 64; o <<= 1) x += __shfl_xor(x, o, 64);
        if (lane == 0) lds[wv][v] = x;
    }
    __syncthreads();
    if (t < 32) {
        float r = (lds[0][t] + lds[1][t]) + (lds[2][t] + lds[3][t]);
        wg[(size_t)(t >> 2) * WIDTH + 4 * kb + (t & 3)] = r;
    }
    __syncthreads();  // lds reuse safety
}

// ---------------------------------------------------------------------------
// Persistent cooperative kernel: 512 blocks (2/CU — fits at any VGPR<=256),
// each block handles strips {bid, bid+512} for BOTH jobs, parity job order.
// grid.sync -> in-register dot vs L2-hot wg -> partial[s] -> grid.sync ->
// block 0 reduces 1024 partials -> out = s*s.
// ---------------------------------------------------------------------------
__global__ __launch_bounds__(256) void persist_kernel(const f32x4* __restrict__ X,
                                                      const f32x4* __restrict__ Wv,
                                                      const f32x4* __restrict__ Gv,
                                                      float* __restrict__ wg,
                                                      float* __restrict__ partial,
                                                      float* __restrict__ out) {
    const int t   = threadIdx.x;
    const int bid = blockIdx.x;        // [0, 512)
    const int s0  = bid, s1 = bid + 512;
    __shared__ float lds[4][32];

    f32x4 a0, a1;
    if (bid & 1) {
        do_gate(Wv, Gv, wg, lds, s0, t);
        a0 = do_colsum(X, s0, t);
        do_gate(Wv, Gv, wg, lds, s1, t);
        a1 = do_colsum(X, s1, t);
    } else {
        a0 = do_colsum(X, s0, t);
        do_gate(Wv, Gv, wg, lds, s0, t);
        a1 = do_colsum(X, s1, t);
        do_gate(Wv, Gv, wg, lds, s1, t);
    }

    cg::this_grid().sync();

    const int lane = t & 63, wvi = t >> 6;
#pragma unroll
    for (int i = 0; i < 2; ++i) {
        const int s = i ? s1 : s0;
        const f32x4 a = i ? a1 : a0;
        const int k4 = (s & 3) * 256 + t;
        const int b  = (s >> 2) & 7;
        f32x4 wv4 = ((const f32x4*)wg)[((size_t)b << 10) + k4];
        float d = a.x * wv4.x + a.y * wv4.y + a.z * wv4.z + a.w * wv4.w;
#pragma unroll
        for (int o = 1; o < 64; o <<= 1) d += __shfl_xor(d, o, 64);
        if (lane == 0) lds[wvi][i] = d;
        __syncthreads();
        if (t == 0) partial[s] = (lds[0][i] + lds[1][i]) + (lds[2][i] + lds[3][i]);
        __syncthreads();
    }

    cg::this_grid().sync();

    if (bid == 0) {
        f32x4 v = ((const f32x4*)partial)[t];  // 256 f32x4 = 1024 floats
        float acc = (v.x + v.y) + (v.z + v.w);
#pragma unroll
        for (int o = 1; o < 64; o <<= 1) acc += __shfl_xor(acc, o, 64);
        if (lane == 0) lds[wvi][2] = acc;
        __syncthreads();
        if (t == 0) {
            float sv = (lds[0][2] + lds[1][2]) + (lds[2][2] + lds[3][2]);
            out[0] = sv * sv;
        }
    }
}

// ======================= fallback: proven R9 pipeline =======================
__global__ __launch_bounds__(256) void fused_kernel(const f32x4* __restrict__ X,
                                                    const f32x4* __restrict__ Wv,
                                                    const f32x4* __restrict__ Gv,
                                                    f32x4* __restrict__ part,
                                                    float* __restrict__ wg) {
    const int t = threadIdx.x;
    if (!(blockIdx.x & 1)) {
        const int s  = blockIdx.x >> 1;
        const int k4 = (s & 3) * 256 + t;
        const int b  = (s >> 2) & 7;
        const int z  = s >> 5;
        const f32x4* p = X + (size_t)(b * ROWS + z * RCH) * (WIDTH / 4) + k4;
        f32x4 a = {0.f, 0.f, 0.f, 0.f};
#pragma unroll 8
        for (int r = 0; r < RCH; ++r) {
            f32x4 v = p[(size_t)r * (WIDTH / 4)];
            a.x += v.x; a.y += v.y; a.z += v.z; a.w += v.w;
        }
        part[((size_t)(z * BATCH + b) << 10) + k4] = a;
    } else {
        const int kb = blockIdx.x >> 1;
        __shared__ float lds[4][32];
        do_gate(Wv, Gv, wg, lds, kb, t);
    }
}

__global__ __launch_bounds__(256) void dot_kernel(const f32x4* __restrict__ part,
                                                  const f32x4* __restrict__ wgv,
                                                  float* __restrict__ partial) {
    const int z  = blockIdx.x >> 3;
    const int kc = blockIdx.x & 7;
    const f32x4* pz = part + ((size_t)z * BATCH << 10);
    float acc = 0.f;
#pragma unroll
    for (int rep = 0; rep < 4; ++rep) {
        const int i = (kc << 10) + rep * 256 + threadIdx.x;
        f32x4 a = pz[i], b = wgv[i];
        acc += a.x * b.x + a.y * b.y + a.z * b.z + a.w * b.w;
    }
#pragma unroll
    for (int o = 1; o < 64; o <<= 1) acc += __shfl_xor(acc, o, 64);
    __shared__ float lds[4];
    const int lane = threadIdx.x & 63, wv = threadIdx.x >> 6;
    if (lane == 0) lds[wv] = acc;
    __syncthreads();
    if (threadIdx.x == 0) partial[blockIdx.x] = (lds[0] + lds[1]) + (lds[2] + lds[3]);
}

__global__ __launch_bounds__(256) void square_kernel(const float* __restrict__ partial,
                                                     int n, float* __restrict__ out) {
    float v = (threadIdx.x < n) ? partial[threadIdx.x] : 0.f;
#pragma unroll
    for (int o = 1; o < 64; o <<= 1) v += __shfl_xor(v, o, 64);
    __shared__ float lds[4];
    const int lane = threadIdx.x & 63, wv = threadIdx.x >> 6;
    if (lane == 0) lds[wv] = v;
    __syncthreads();
    if (threadIdx.x == 0) {
        float s = (lds[0] + lds[1]) + (lds[2] + lds[3]);
        out[0] = s * s;
    }
}

extern "C" void kernel_launch(void* const* d_in, const int* in_sizes, int n_in,
                              void* d_out, int out_size, void* d_ws, size_t ws_size,
                              hipStream_t stream) {
    const f32x4* X  = (const f32x4*)d_in[0];  // (8, 2048, 4096)
    const f32x4* Wv = (const f32x4*)d_in[1];  // (4096, 4096)
    const f32x4* Gv = (const f32x4*)d_in[2];  // (8, 1024, 1024)
    float* out = (float*)d_out;               // scalar

    float* part    = (float*)d_ws;                              // 4 MB (fallback only)
    float* wg      = part + (size_t)ZPART * BATCH * WIDTH;      // 32768 f32
    float* partial = wg + (size_t)BATCH * WIDTH;                // 1024 f32

    void* args[] = {(void*)&X, (void*)&Wv, (void*)&Gv,
                    (void*)&wg, (void*)&partial, (void*)&out};
    hipError_t rc = hipLaunchCooperativeKernel((const void*)persist_kernel,
                                               dim3(512), dim3(256), args, 0, stream);
    if (rc != hipSuccess) {
        // proven R9 pipeline (77.5 us)
        fused_kernel<<<2048, 256, 0, stream>>>(X, Wv, Gv, (f32x4*)part, wg);
        dot_kernel<<<NDOT, 256, 0, stream>>>((const f32x4*)part, (const f32x4*)wg, partial);
        square_kernel<<<1, 256, 0, stream>>>(partial, 256, out);
    }
}

// Round 16
// 77.785 us; speedup vs baseline: 2.6159x; 2.6159x over previous
//
#include <hip/hip_runtime.h>
#include <hip/hip_cooperative_groups.h>

namespace cg = cooperative_groups;

#define BATCH 8
#define ROWS  2048
#define WIDTH 4096
#define COLS  4096
#define KB    1024   // WIDTH/4 gating blocks along k
#define CBV   1024   // COLS/4  float4s per W row
#define ZPART 32
#define RCH   64     // rows per colsum strip
#define NDOT  256
#define NJOBS 2048   // 1024 colsum strips (even j) + 1024 gate rows (odd j)

typedef float f32x4 __attribute__((ext_vector_type(4)));

// ---- colsum strip s: register-held column sums (R9-proven loop) ------------
__device__ __forceinline__ f32x4 do_colsum(const f32x4* __restrict__ X, int s, int t) {
    const int k4 = (s & 3) * 256 + t;
    const int b  = (s >> 2) & 7;
    const int z  = s >> 5;
    const f32x4* p = X + (size_t)(b * ROWS + z * RCH) * (WIDTH / 4) + k4;
    f32x4 a = {0.f, 0.f, 0.f, 0.f};
#pragma unroll 8
    for (int r = 0; r < RCH; ++r) {
        f32x4 v = p[(size_t)r * (WIDTH / 4)];
        a.x += v.x; a.y += v.y; a.z += v.z; a.w += v.w;
    }
    return a;
}

// ---- gate row kb (R9-proven; j-pair W loads keep VGPR at 64) ---------------
__device__ __forceinline__ void do_gate(const f32x4* __restrict__ Wv,
                                        const f32x4* __restrict__ Gv,
                                        float* __restrict__ wg,
                                        float lds[4][32], int kb, int t) {
    const int lane = t & 63, wv = t >> 6;

    f32x4 g[8];
#pragma unroll
    for (int b = 0; b < 8; ++b)
        g[b] = Gv[((size_t)(b * KB + kb) << 8) + t];

    float w4[4][4];
#pragma unroll
    for (int jp = 0; jp < 2; ++jp) {
        f32x4 wj[2][4];
#pragma unroll
        for (int j = 0; j < 2; ++j)
#pragma unroll
            for (int m = 0; m < 4; ++m)
                wj[j][m] = Wv[(size_t)(4 * kb + 2 * jp + j) * CBV + 4 * t + m];
#pragma unroll
        for (int j = 0; j < 2; ++j)
#pragma unroll
            for (int m = 0; m < 4; ++m)
                w4[2 * jp + j][m] = (wj[j][m].x + wj[j][m].y) + (wj[j][m].z + wj[j][m].w);
    }

    float acc[8][4];
#pragma unroll
    for (int b = 0; b < 8; ++b)
#pragma unroll
        for (int j = 0; j < 4; ++j)
            acc[b][j] = g[b].x * w4[j][0] + g[b].y * w4[j][1] +
                        g[b].z * w4[j][2] + g[b].w * w4[j][3];

#pragma unroll
    for (int v = 0; v < 32; ++v) {
        float x = acc[v >> 2][v & 3];
#pragma unroll
        for (int o = 1; o < 64; o <<= 1) x += __shfl_xor(x, o, 64);
        if (lane == 0) lds[wv][v] = x;
    }
    __syncthreads();
    if (t < 32) {
        float r = (lds[0][t] + lds[1][t]) + (lds[2][t] + lds[3][t]);
        wg[(size_t)(t >> 2) * WIDTH + 4 * kb + (t & 3)] = r;
    }
    __syncthreads();  // lds reuse safety
}

// ---------------------------------------------------------------------------
// Cooperative persistent kernel, grid = 2048 (1 job/block) or 1024 (2 jobs).
// Job j: even -> colsum strip j/2 (sums stay in REGISTERS); odd -> gate row.
// grid.sync -> colsum blocks dot their register sums vs L2-hot wg ->
// partial[s] -> grid.sync -> block 0 reduces 1024 partials -> out = s^2.
// No part array, no dot/square kernels, no launch gaps.
// ---------------------------------------------------------------------------
__global__ __launch_bounds__(256) void persist2_kernel(const f32x4* __restrict__ X,
                                                       const f32x4* __restrict__ Wv,
                                                       const f32x4* __restrict__ Gv,
                                                       float* __restrict__ wg,
                                                       float* __restrict__ partial,
                                                       float* __restrict__ out) {
    const int t  = threadIdx.x;
    const int nb = gridDim.x;
    __shared__ float lds[4][32];

    f32x4 a;
    int my_s = -1;  // block-uniform: the one colsum strip this block owns (if any)
    for (int j = blockIdx.x; j < NJOBS; j += nb) {
        if (!(j & 1)) { my_s = j >> 1; a = do_colsum(X, my_s, t); }
        else          do_gate(Wv, Gv, wg, lds, j >> 1, t);
    }

    cg::this_grid().sync();

    const int lane = t & 63, wvi = t >> 6;
    if (my_s >= 0) {  // block-uniform branch
        const int k4 = (my_s & 3) * 256 + t;
        const int b  = (my_s >> 2) & 7;
        f32x4 wv4 = ((const f32x4*)wg)[((size_t)b << 10) + k4];
        float d = a.x * wv4.x + a.y * wv4.y + a.z * wv4.z + a.w * wv4.w;
#pragma unroll
        for (int o = 1; o < 64; o <<= 1) d += __shfl_xor(d, o, 64);
        if (lane == 0) lds[wvi][0] = d;
        __syncthreads();
        if (t == 0) partial[my_s] = (lds[0][0] + lds[1][0]) + (lds[2][0] + lds[3][0]);
    }

    cg::this_grid().sync();

    if (blockIdx.x == 0) {
        f32x4 v = ((const f32x4*)partial)[t];  // 256 f32x4 = 1024 floats
        float acc = (v.x + v.y) + (v.z + v.w);
#pragma unroll
        for (int o = 1; o < 64; o <<= 1) acc += __shfl_xor(acc, o, 64);
        if (lane == 0) lds[wvi][1] = acc;
        __syncthreads();
        if (t == 0) {
            float sv = (lds[0][1] + lds[1][1]) + (lds[2][1] + lds[3][1]);
            out[0] = sv * sv;
        }
    }
}

// ======================= fallback: proven R9 pipeline =======================
__global__ __launch_bounds__(256) void fused_kernel(const f32x4* __restrict__ X,
                                                    const f32x4* __restrict__ Wv,
                                                    const f32x4* __restrict__ Gv,
                                                    f32x4* __restrict__ part,
                                                    float* __restrict__ wg) {
    const int t = threadIdx.x;
    if (!(blockIdx.x & 1)) {
        const int s = blockIdx.x >> 1;
        f32x4 a = do_colsum(X, s, t);
        const int k4 = (s & 3) * 256 + t;
        const int b  = (s >> 2) & 7;
        const int z  = s >> 5;
        part[((size_t)(z * BATCH + b) << 10) + k4] = a;
    } else {
        __shared__ float lds[4][32];
        do_gate(Wv, Gv, wg, lds, blockIdx.x >> 1, t);
    }
}

__global__ __launch_bounds__(256) void dot_kernel(const f32x4* __restrict__ part,
                                                  const f32x4* __restrict__ wgv,
                                                  float* __restrict__ partial) {
    const int z  = blockIdx.x >> 3;
    const int kc = blockIdx.x & 7;
    const f32x4* pz = part + ((size_t)z * BATCH << 10);
    float acc = 0.f;
#pragma unroll
    for (int rep = 0; rep < 4; ++rep) {
        const int i = (kc << 10) + rep * 256 + threadIdx.x;
        f32x4 a = pz[i], b = wgv[i];
        acc += a.x * b.x + a.y * b.y + a.z * b.z + a.w * b.w;
    }
#pragma unroll
    for (int o = 1; o < 64; o <<= 1) acc += __shfl_xor(acc, o, 64);
    __shared__ float lds[4];
    const int lane = threadIdx.x & 63, wv = threadIdx.x >> 6;
    if (lane == 0) lds[wv] = acc;
    __syncthreads();
    if (threadIdx.x == 0) partial[blockIdx.x] = (lds[0] + lds[1]) + (lds[2] + lds[3]);
}

__global__ __launch_bounds__(256) void square_kernel(const float* __restrict__ partial,
                                                     float* __restrict__ out) {
    float v = partial[threadIdx.x];
#pragma unroll
    for (int o = 1; o < 64; o <<= 1) v += __shfl_xor(v, o, 64);
    __shared__ float lds[4];
    const int lane = threadIdx.x & 63, wv = threadIdx.x >> 6;
    if (lane == 0) lds[wv] = v;
    __syncthreads();
    if (threadIdx.x == 0) {
        float s = (lds[0] + lds[1]) + (lds[2] + lds[3]);
        out[0] = s * s;
    }
}

extern "C" void kernel_launch(void* const* d_in, const int* in_sizes, int n_in,
                              void* d_out, int out_size, void* d_ws, size_t ws_size,
                              hipStream_t stream) {
    const f32x4* X  = (const f32x4*)d_in[0];  // (8, 2048, 4096)
    const f32x4* Wv = (const f32x4*)d_in[1];  // (4096, 4096)
    const f32x4* Gv = (const f32x4*)d_in[2];  // (8, 1024, 1024)
    float* out = (float*)d_out;               // scalar

    float* part    = (float*)d_ws;                          // 4 MB (fallback only)
    float* wg      = part + (size_t)ZPART * BATCH * WIDTH;  // 32768 f32
    float* partial = wg + (size_t)BATCH * WIDTH;            // 1024 f32

    // capture-time occupancy query (host-side, deterministic)
    int maxB = 0;
    hipError_t qrc = hipOccupancyMaxActiveBlocksPerMultiprocessor(
        &maxB, (const void*)persist2_kernel, 256, 0);
    int capacity = (qrc == hipSuccess) ? maxB * 256 : 0;  // 256 CUs
    int grid = (capacity >= 2048) ? 2048 : (capacity >= 1024 ? 1024 : 0);

    hipError_t rc = hipErrorUnknown;
    if (grid > 0) {
        void* args[] = {(void*)&X, (void*)&Wv, (void*)&Gv,
                        (void*)&wg, (void*)&partial, (void*)&out};
        rc = hipLaunchCooperativeKernel((const void*)persist2_kernel,
                                        dim3(grid), dim3(256), args, 0, stream);
    }
    if (rc != hipSuccess) {
        // proven R9 pipeline (77.5 us)
        fused_kernel<<<2048, 256, 0, stream>>>(X, Wv, Gv, (f32x4*)part, wg);
        dot_kernel<<<NDOT, 256, 0, stream>>>((const f32x4*)part, (const f32x4*)wg, partial);
        square_kernel<<<1, 256, 0, stream>>>(partial, out);
    }
}

// Round 17
// 77.620 us; speedup vs baseline: 2.6215x; 1.0021x over previous
//
#include <hip/hip_runtime.h>

#define BATCH 8
#define ROWS  2048
#define WIDTH 4096
#define COLS  4096
#define KB    1024   // WIDTH/4 gating blocks along k
#define CBV   1024   // COLS/4  float4s per W row
#define ZPART 32     // row-chunks per batch (partials)
#define RCH   64     // ROWS / ZPART
#define NDOT  256    // dot-kernel blocks (z x k-chunk)

typedef float f32x4 __attribute__((ext_vector_type(4)));

// ---------------------------------------------------------------------------
// Fused kernel, 2048 blocks, parity-interleaved so both streams co-reside
// (parity mixing measured best: contiguous split +6us, R12; slabs +9us, R3):
//   even bid (1024): colsum — part[z][b][k] = sum_{r in chunk z} X[b,r,k]
//   odd  bid (1024): gate   — wg[b, 4kb+j] = sum_c W[4kb+j, c] * G[b, kb, c/4]
// No atomics (R7: +8us), no device-scope fences (R4/R5: 4x slowdown),
// no NT hints (R4/R11: regress), plain cached loads/stores.
// ---------------------------------------------------------------------------
__global__ __launch_bounds__(256) void fused_kernel(const f32x4* __restrict__ X,
                                                    const f32x4* __restrict__ Wv,
                                                    const f32x4* __restrict__ Gv,
                                                    f32x4* __restrict__ part,
                                                    float* __restrict__ wg) {
    const int t = threadIdx.x;
    if (!(blockIdx.x & 1)) {
        // ---------------- colsum: strip pattern (proven) --------------------
        const int s  = blockIdx.x >> 1;     // [0, 1024)
        const int k4 = (s & 3) * 256 + t;   // [0, 1024)
        const int b  = (s >> 2) & 7;
        const int z  = s >> 5;              // [0, 32)

        const f32x4* p = X + (size_t)(b * ROWS + z * RCH) * (WIDTH / 4) + k4;
        f32x4 a = {0.f, 0.f, 0.f, 0.f};
#pragma unroll 8
        for (int r = 0; r < RCH; ++r) {
            f32x4 v = p[(size_t)r * (WIDTH / 4)];
            a.x += v.x; a.y += v.y; a.z += v.z; a.w += v.w;
        }
        part[((size_t)(z * BATCH + b) << 10) + k4] = a;
    } else {
        // ---------------- gate: one block per kb ----------------------------
        const int kb = blockIdx.x >> 1;     // [0, 1024)
        const int lane = t & 63, wv = t >> 6;

        f32x4 w[4][4];  // [j][m]: W[4kb+j, 4*(4t+m) .. +3]
#pragma unroll
        for (int j = 0; j < 4; ++j)
#pragma unroll
            for (int m = 0; m < 4; ++m)
                w[j][m] = Wv[(size_t)(4 * kb + j) * CBV + 4 * t + m];

        f32x4 g[8];     // G[b, kb, 4t..4t+3]
#pragma unroll
        for (int b = 0; b < 8; ++b)
            g[b] = Gv[((size_t)(b * KB + kb) << 8) + t];

        float w4[4][4];  // 4-col block sums of W
#pragma unroll
        for (int j = 0; j < 4; ++j)
#pragma unroll
            for (int m = 0; m < 4; ++m)
                w4[j][m] = (w[j][m].x + w[j][m].y) + (w[j][m].z + w[j][m].w);

        float acc[8][4];
#pragma unroll
        for (int b = 0; b < 8; ++b)
#pragma unroll
            for (int j = 0; j < 4; ++j)
                acc[b][j] = g[b].x * w4[j][0] + g[b].y * w4[j][1] +
                            g[b].z * w4[j][2] + g[b].w * w4[j][3];

        // reduce 32 accumulators (b,j) across 256 threads (proven form;
        // fold-butterfly variant regressed, R10)
        __shared__ float lds[4][32];
#pragma unroll
        for (int v = 0; v < 32; ++v) {
            float x = acc[v >> 2][v & 3];
#pragma unroll
            for (int o = 1; o < 64; o <<= 1) x += __shfl_xor(x, o, 64);
            if (lane == 0) lds[wv][v] = x;
        }
        __syncthreads();
        if (t < 32) {
            float r = (lds[0][t] + lds[1][t]) + (lds[2][t] + lds[3][t]);
            wg[(size_t)(t >> 2) * WIDTH + 4 * kb + (t & 3)] = r;
        }
    }
}

// ---------------------------------------------------------------------------
// F1: 256 blocks — block (z = bid>>3, kc = bid&7) dots a 16 KB slice of
// part[z] against the matching wg slice (wg chunks go L2-hot).
// (32-block version was a per-CU-BW-limited 11 us tail, R8.)
// ---------------------------------------------------------------------------
__global__ __launch_bounds__(256) void dot_kernel(const f32x4* __restrict__ part,
                                                  const f32x4* __restrict__ wgv,
                                                  float* __restrict__ partial) {
    const int z  = blockIdx.x >> 3;  // [0, 32)
    const int kc = blockIdx.x & 7;   // [0, 8)
    const f32x4* pz = part + ((size_t)z * BATCH << 10);

    float acc = 0.f;
#pragma unroll
    for (int rep = 0; rep < 4; ++rep) {
        const int i = (kc << 10) + rep * 256 + threadIdx.x;
        f32x4 a = pz[i], b = wgv[i];
        acc += a.x * b.x + a.y * b.y + a.z * b.z + a.w * b.w;
    }
#pragma unroll
    for (int o = 1; o < 64; o <<= 1) acc += __shfl_xor(acc, o, 64);
    __shared__ float lds[4];
    const int lane = threadIdx.x & 63, wv = threadIdx.x >> 6;
    if (lane == 0) lds[wv] = acc;
    __syncthreads();
    if (threadIdx.x == 0) partial[blockIdx.x] = (lds[0] + lds[1]) + (lds[2] + lds[3]);
}

// ---------------------------------------------------------------------------
// F2: s = sum(partial[0..256)); out[0] = s*s. One 256-thread block.
// ---------------------------------------------------------------------------
__global__ __launch_bounds__(256) void square_kernel(const float* __restrict__ partial,
                                                     float* __restrict__ out) {
    float v = partial[threadIdx.x];
#pragma unroll
    for (int o = 1; o < 64; o <<= 1) v += __shfl_xor(v, o, 64);
    __shared__ float lds[4];
    const int lane = threadIdx.x & 63, wv = threadIdx.x >> 6;
    if (lane == 0) lds[wv] = v;
    __syncthreads();
    if (threadIdx.x == 0) {
        float s = (lds[0] + lds[1]) + (lds[2] + lds[3]);
        out[0] = s * s;
    }
}

extern "C" void kernel_launch(void* const* d_in, const int* in_sizes, int n_in,
                              void* d_out, int out_size, void* d_ws, size_t ws_size,
                              hipStream_t stream) {
    const float* X = (const float*)d_in[0];  // (8, 2048, 4096)
    const float* W = (const float*)d_in[1];  // (4096, 4096)
    const float* G = (const float*)d_in[2];  // (8, 1024, 1024)
    float* out = (float*)d_out;              // scalar

    float* part    = (float*)d_ws;                           // 4 MB, fully rewritten
    float* wg      = part + (size_t)ZPART * BATCH * WIDTH;   // 128 KB, fully rewritten
    float* partial = wg + (size_t)BATCH * WIDTH;             // 256 f32, fully rewritten

    fused_kernel<<<2048, 256, 0, stream>>>((const f32x4*)X, (const f32x4*)W,
                                           (const f32x4*)G, (f32x4*)part, wg);

    dot_kernel<<<NDOT, 256, 0, stream>>>((const f32x4*)part, (const f32x4*)wg, partial);

    square_kernel<<<1, 256, 0, stream>>>(partial, out);
}